// Round 3
// baseline (1195.661 us; speedup 1.0000x reference)
//
#include <hip/hip_runtime.h>

#define BB 16
#define CC 32
#define KK 4
#define CKD 128     // C*K
#define NN 8192
#define NLEV 13
#define AL 128      // ALPHA (weight mode-axis storage stride)
#define PMAX 12     // max K-split for fwd DFT (scratch: scrD in Uall+Vall, scrS in usT)

struct LevTab { int off[NLEV]; int n[NLEV]; int l[NLEV]; int total; };
struct MixTab2 { long long off[NLEV]; int l[NLEV]; int mcum[NLEV]; };

// tw [j][m] and twT [m][j]; value = (cos,sin)(2*pi*((j*m) mod n)/n)
__global__ void twiddle_fill_k(float2* __restrict__ tw, float2* __restrict__ twT, LevTab t) {
  int idx = blockIdx.x * blockDim.x + threadIdx.x;
  if (idx >= t.total) return;
  int lev = 0;
  for (int q = 1; q < NLEV; q++) lev = (idx >= t.off[q]) ? q : lev;
  int r = idx - t.off[lev];
  int n = t.n[lev], l = t.l[lev];
  int j = r / l, m = r - j * l;
  long long pp = ((long long)j * (long long)m) % n;
  float ang = (float)((double)pp * (6.283185307179586476925286766559 / (double)n));
  float s, c;
  sincosf(ang, &s, &c);
  float2 v = make_float2(c, s);
  tw[t.off[lev] + j * l + m] = v;
  twT[t.off[lev] + m * n + j] = v;
}

// x:(B,2n,C,K) -> s:(B,n,C,K), d:(B,n,C,K)
__global__ void decompose_k(const float* __restrict__ xin, float* __restrict__ sout,
                            float* __restrict__ dout,
                            const float* __restrict__ ecs, const float* __restrict__ ecd,
                            int nh) {
  int idx = blockIdx.x * blockDim.x + threadIdx.x;
  if (idx >= BB * nh * CC) return;
  int c = idx & (CC - 1);
  int t = idx / CC;
  int j = t % nh;
  int b = t / nh;
  size_t ib = (((size_t)b * (2 * nh) + 2 * j) * CC + c) * KK;
  float4 xe = *(const float4*)(xin + ib);
  float4 xo = *(const float4*)(xin + ib + CC * KK);
  float xa[8] = {xe.x, xe.y, xe.z, xe.w, xo.x, xo.y, xo.z, xo.w};
  float sv[4] = {0.f,0.f,0.f,0.f}, dv[4] = {0.f,0.f,0.f,0.f};
  #pragma unroll
  for (int p = 0; p < 8; p++) {
    float v = xa[p];
    #pragma unroll
    for (int k = 0; k < 4; k++) {
      sv[k] = fmaf(v, ecs[p*4+k], sv[k]);
      dv[k] = fmaf(v, ecd[p*4+k], dv[k]);
    }
  }
  size_t ob = (((size_t)b * nh + j) * CC + c) * KK;
  *(float4*)(sout + ob) = make_float4(sv[0], sv[1], sv[2], sv[3]);
  *(float4*)(dout + ob) = make_float4(dv[0], dv[1], dv[2], dv[3]);
}

// ---- tiled forward DFT: Xf[b,i,m] = sum_j v[b,j,i]*(cos,-sin)(jm) ----
// block 256 = 16tx(m) x 16ty(i); tile 64i x 64m; K = j chunked 16, split P ways.
// grid: x = ceil(l/64), y = b*2+itile, z = srcs*P + ks
__global__ void fwd_dft_t(const float* __restrict__ dsrc, const float* __restrict__ ssrc,
                          float2* __restrict__ Dp, float2* __restrict__ Sp,
                          const float2* __restrict__ tw, int n, int l, int P, int chunk) {
  __shared__ float As[16][64];
  __shared__ float Bc[16][64];
  __shared__ float Bn[16][64];
  int zz = blockIdx.z;
  int srcs = (zz >= P) ? 1 : 0;
  int ks = zz - srcs * P;
  const float* __restrict__ src = srcs ? ssrc : dsrc;
  size_t spcl = (size_t)BB * CKD * l;
  float2* __restrict__ dst = (srcs ? Sp : Dp) + (size_t)ks * spcl;
  int m0 = blockIdx.x << 6;
  int by = blockIdx.y;
  int it = by & 1, b = by >> 1;
  int i0 = it << 6;
  int tid = threadIdx.x;
  int tx = tid & 15, ty = tid >> 4;
  int k_start = ks * chunk;
  int k_cnt = n - k_start;
  if (k_cnt > chunk) k_cnt = chunk;
  float are[4][4], aim[4][4];
  #pragma unroll
  for (int a = 0; a < 4; a++)
    #pragma unroll
    for (int d = 0; d < 4; d++) { are[a][d] = 0.f; aim[a][d] = 0.f; }

  for (int j0 = 0; j0 < k_cnt; j0 += 16) {
    { // stage A: 16 j-rows x 64 i floats
      int row = tid >> 4;
      int c4 = (tid & 15) << 2;
      float4 v = make_float4(0.f,0.f,0.f,0.f);
      if (j0 + row < k_cnt) {
        int jg = k_start + j0 + row;
        v = *(const float4*)(src + ((size_t)b * n + jg) * CKD + i0 + c4);
      }
      *(float4*)&As[row][c4] = v;
    }
    #pragma unroll
    for (int it2 = 0; it2 < 2; it2++) { // stage twiddles into cos/sin planes
      int idx = tid + (it2 << 8);
      int row = idx >> 5;
      int cm = (idx & 31) << 1;
      float4 v = make_float4(0.f,0.f,0.f,0.f);
      if (j0 + row < k_cnt) {
        int jg = k_start + j0 + row;
        int mg = m0 + cm;
        if (mg + 1 < l) v = *(const float4*)(tw + (size_t)jg * l + mg);
        else if (mg < l) { float2 t2 = tw[(size_t)jg * l + mg]; v.x = t2.x; v.y = t2.y; }
      }
      Bc[row][cm] = v.x;  Bn[row][cm] = v.y;
      Bc[row][cm+1] = v.z; Bn[row][cm+1] = v.w;
    }
    __syncthreads();
    #pragma unroll
    for (int j = 0; j < 16; j++) {
      float av[4], cr[4], ci[4];
      *(float4*)av = *(const float4*)&As[j][ty << 2];
      *(float4*)cr = *(const float4*)&Bc[j][tx << 2];
      *(float4*)ci = *(const float4*)&Bn[j][tx << 2];
      #pragma unroll
      for (int ii = 0; ii < 4; ii++)
        #pragma unroll
        for (int mm = 0; mm < 4; mm++) {
          are[ii][mm] = fmaf(av[ii],  cr[mm], are[ii][mm]);
          aim[ii][mm] = fmaf(av[ii], -ci[mm], aim[ii][mm]);
        }
    }
    __syncthreads();
  }
  #pragma unroll
  for (int ii = 0; ii < 4; ii++) {
    int i = i0 + (ty << 2) + ii;
    #pragma unroll
    for (int mm = 0; mm < 4; mm++) {
      int m = m0 + (tx << 2) + mm;
      if (m < l) dst[((size_t)b * CKD + i) * l + m] = make_float2(are[ii][mm], aim[ii][mm]);
    }
  }
}

// sum P partial spectra (scratch) into compact Dall/Sall slots
__global__ void reduce_k(float4* __restrict__ dD, float4* __restrict__ dS,
                         const float4* __restrict__ pD, const float4* __restrict__ pS,
                         int cnt4, int P) {
  int idx = blockIdx.x * blockDim.x + threadIdx.x;
  if (idx >= 2 * cnt4) return;
  const float4* src = (idx < cnt4) ? pD : pS;
  float4* dst = (idx < cnt4) ? dD : dS;
  int e = (idx < cnt4) ? idx : idx - cnt4;
  float4 a = src[e];
  for (int p = 1; p < P; p++) {
    float4 v = src[(size_t)p * cnt4 + e];
    a.x += v.x; a.y += v.y; a.z += v.z; a.w += v.w;
  }
  dst[e] = a;
}

// weight transpose: W[i][o][m] (re,im separate) -> Wt[m][i][o] interleaved float2
// grid (i=CKD, ochunk=4, tensor=3), block 256
__global__ void wtr_k(const float* __restrict__ Ar, const float* __restrict__ Ai,
                      const float* __restrict__ Br, const float* __restrict__ Bi,
                      const float* __restrict__ Cr, const float* __restrict__ Ci,
                      float2* __restrict__ WtA, float2* __restrict__ WtB,
                      float2* __restrict__ WtC) {
  __shared__ float2 Ts[32][130];   // padded: load-phase bank spread
  int i = blockIdx.x;
  int o0 = blockIdx.y << 5;
  int z = blockIdx.z;
  const float* Wr = (z == 0) ? Ar : ((z == 1) ? Br : Cr);
  const float* Wi = (z == 0) ? Ai : ((z == 1) ? Bi : Ci);
  float2* Wt = (z == 0) ? WtA : ((z == 1) ? WtB : WtC);
  int tid = threadIdx.x;
  { // load 32 o x 128 m, coalesced over m
    int o = tid >> 3, m0 = (tid & 7) << 4;
    const float* rp = Wr + ((size_t)i * CKD + o0 + o) * AL + m0;
    const float* ip = Wi + ((size_t)i * CKD + o0 + o) * AL + m0;
    #pragma unroll
    for (int r = 0; r < 4; r++) {
      float4 vr = *(const float4*)(rp + r * 4);
      float4 vi = *(const float4*)(ip + r * 4);
      Ts[o][m0 + r*4 + 0] = make_float2(vr.x, vi.x);
      Ts[o][m0 + r*4 + 1] = make_float2(vr.y, vi.y);
      Ts[o][m0 + r*4 + 2] = make_float2(vr.z, vi.z);
      Ts[o][m0 + r*4 + 3] = make_float2(vr.w, vi.w);
    }
  }
  __syncthreads();
  { // store 128 m x 32 o, coalesced over o
    int m = tid >> 1, oh = (tid & 1) << 4;
    float2* wp = Wt + ((size_t)m * CKD + i) * CKD + o0 + oh;
    #pragma unroll
    for (int r = 0; r < 16; r += 2) {
      float2 e0 = Ts[oh + r][m];
      float2 e1 = Ts[oh + r + 1][m];
      *(float4*)(wp + r) = make_float4(e0.x, e0.y, e1.x, e1.y);
    }
  }
}

// batched per-(lev,m) complex GEMM: U[b,o] = sum_i D[b,i]*A[i,o] + S[b,i]*B[i,o]
//                                   V[b,o] = sum_i D[b,i]*C[i,o]
// grid.x = sum_q l_q; block 256 = 128 o-lanes x 2 b-halves (8 b each)
__global__ void __launch_bounds__(256)
mix2_k(const float2* __restrict__ Dall, const float2* __restrict__ Sall,
       const float2* __restrict__ WA, const float2* __restrict__ WB,
       const float2* __restrict__ WC,
       float2* __restrict__ Uall, float2* __restrict__ Vall, MixTab2 mt) {
  __shared__ __align__(16) float2 Dl[CKD][BB];
  __shared__ __align__(16) float2 Sl[CKD][BB];
  int bx = blockIdx.x;
  int lev = 0;
  #pragma unroll
  for (int q = 1; q < NLEV; q++) lev = (bx >= mt.mcum[q]) ? q : lev;
  int m = bx - mt.mcum[lev];
  int l = mt.l[lev];
  const float2* __restrict__ D = Dall + mt.off[lev];
  const float2* __restrict__ S = Sall + mt.off[lev];
  float2* __restrict__ U = Uall + mt.off[lev];
  float2* __restrict__ V = Vall + mt.off[lev];
  int tid = threadIdx.x;
  int o = tid & (CKD - 1), bh = tid >> 7;
  { // stage D,S slice for this mode into LDS as [i][b]
    int b = tid & 15, i0 = (tid >> 4) << 3;
    #pragma unroll
    for (int r = 0; r < 8; r++) {
      int i = i0 + r;
      size_t g = ((size_t)b * CKD + i) * l + m;
      Dl[i][b] = D[g];
      Sl[i][b] = S[g];
    }
  }
  __syncthreads();
  float ur[8], ui[8], vr[8], vi[8];
  #pragma unroll
  for (int r = 0; r < 8; r++) { ur[r] = 0.f; ui[r] = 0.f; vr[r] = 0.f; vi[r] = 0.f; }
  const float2* wa = WA + (size_t)m * CKD * CKD + o;
  const float2* wb = WB + (size_t)m * CKD * CKD + o;
  const float2* wc = WC + (size_t)m * CKD * CKD + o;
  #pragma unroll 4
  for (int i = 0; i < CKD; i++) {
    float2 a  = wa[(size_t)i * CKD];
    float2 bw = wb[(size_t)i * CKD];
    float2 cw = wc[(size_t)i * CKD];
    float2 dv[8], sv[8];
    #pragma unroll
    for (int r = 0; r < 4; r++) {
      *(float4*)&dv[r*2] = *(const float4*)&Dl[i][(bh << 3) + r*2];
      *(float4*)&sv[r*2] = *(const float4*)&Sl[i][(bh << 3) + r*2];
    }
    #pragma unroll
    for (int r = 0; r < 8; r++) {
      float2 d = dv[r], s = sv[r];
      ur[r] = fmaf(d.x, a.x, ur[r]);  ur[r] = fmaf(-d.y, a.y, ur[r]);
      ur[r] = fmaf(s.x, bw.x, ur[r]); ur[r] = fmaf(-s.y, bw.y, ur[r]);
      ui[r] = fmaf(d.x, a.y, ui[r]);  ui[r] = fmaf(d.y, a.x, ui[r]);
      ui[r] = fmaf(s.x, bw.y, ui[r]); ui[r] = fmaf(s.y, bw.x, ui[r]);
      vr[r] = fmaf(d.x, cw.x, vr[r]); vr[r] = fmaf(-d.y, cw.y, vr[r]);
      vi[r] = fmaf(d.x, cw.y, vi[r]); vi[r] = fmaf(d.y, cw.x, vi[r]);
    }
  }
  #pragma unroll
  for (int r = 0; r < 8; r++) {
    int b = (bh << 3) + r;
    size_t ob = ((size_t)b * l + m) * CKD + o;
    U[ob] = make_float2(ur[r], ui[r]);
    V[ob] = make_float2(vr[r], vi[r]);
  }
}

// ---- tiled inverse DFT (v2: 64j x 128o tile, 4j x 8o per thread) ----
// y[b,j,o] = (2*sum_{m=0..l-1}(Gr*cos - Gi*sin) - G0.re - nyq*(-1)^j*G[l-1].re)/n
// grid: x = ceil(n/64), y = b, z = {U->ud, V->us}
__global__ void __launch_bounds__(256)
inv_dft_t(const float2* __restrict__ Uf, const float2* __restrict__ Vf,
          float* __restrict__ ud, float* __restrict__ us,
          const float2* __restrict__ twT, int n, int l, int nyq) {
  __shared__ float Gr[16][128];
  __shared__ float Gi[16][128];
  __shared__ float2 Ts[16][64];
  int z = blockIdx.z;
  const float2* __restrict__ G = (z ? Vf : Uf);
  float* __restrict__ out = (z ? us : ud);
  int j0 = blockIdx.x << 6;
  int b = blockIdx.y;
  int tid = threadIdx.x;
  int tx = tid & 15, ty = tid >> 4;   // tx -> o (2x4), ty -> j (4)
  float acc[4][8];
  #pragma unroll
  for (int a = 0; a < 4; a++)
    #pragma unroll
    for (int d = 0; d < 8; d++) acc[a][d] = 0.f;

  for (int m0 = 0; m0 < l; m0 += 16) {
    #pragma unroll
    for (int it2 = 0; it2 < 4; it2++) { // stage G rows (16m x 128o) into re/im planes
      int idx = tid + (it2 << 8);
      int row = idx >> 6;
      int co = (idx & 63) << 1;
      float4 v = make_float4(0.f,0.f,0.f,0.f);
      if (m0 + row < l)
        v = *(const float4*)(G + ((size_t)b * l + m0 + row) * CKD + co);
      Gr[row][co] = v.x;   Gi[row][co] = v.y;
      Gr[row][co+1] = v.z; Gi[row][co+1] = v.w;
    }
    #pragma unroll
    for (int it2 = 0; it2 < 2; it2++) { // stage twT tile (16m x 64j)
      int idx = tid + (it2 << 8);
      int row = idx >> 5;
      int cj = (idx & 31) << 1;
      float4 v = make_float4(0.f,0.f,0.f,0.f);
      if (m0 + row < l) {
        int jg = j0 + cj;
        if (jg + 1 < n) v = *(const float4*)(twT + (size_t)(m0 + row) * n + jg);
        else if (jg < n) { float2 t2 = twT[(size_t)(m0 + row) * n + jg]; v.x = t2.x; v.y = t2.y; }
      }
      *(float4*)&Ts[row][cj] = v;
    }
    __syncthreads();
    #pragma unroll
    for (int mm = 0; mm < 16; mm++) {
      float gr[8], gi[8];
      float2 cs[4];
      *(float4*)&gr[0] = *(const float4*)&Gr[mm][tx << 2];
      *(float4*)&gr[4] = *(const float4*)&Gr[mm][64 + (tx << 2)];
      *(float4*)&gi[0] = *(const float4*)&Gi[mm][tx << 2];
      *(float4*)&gi[4] = *(const float4*)&Gi[mm][64 + (tx << 2)];
      *(float4*)&cs[0] = *(const float4*)&Ts[mm][ty << 2];
      *(float4*)&cs[2] = *(const float4*)&Ts[mm][(ty << 2) + 2];
      #pragma unroll
      for (int jj = 0; jj < 4; jj++)
        #pragma unroll
        for (int oo = 0; oo < 8; oo++) {
          acc[jj][oo] = fmaf(gr[oo],  cs[jj].x, acc[jj][oo]);
          acc[jj][oo] = fmaf(gi[oo], -cs[jj].y, acc[jj][oo]);
        }
    }
    __syncthreads();
  }
  float invn = 1.f / (float)n;
  float g0[8], gn[8];
  #pragma unroll
  for (int oo = 0; oo < 8; oo++) {
    int o = ((oo >> 2) << 6) + (tx << 2) + (oo & 3);
    g0[oo] = G[((size_t)b * l) * CKD + o].x;
    gn[oo] = nyq ? G[((size_t)b * l + (l - 1)) * CKD + o].x : 0.f;
  }
  #pragma unroll
  for (int jj = 0; jj < 4; jj++) {
    int j = j0 + (ty << 2) + jj;
    if (j < n) {
      float sgn = (j & 1) ? -1.f : 1.f;
      float4 y0, y1;
      float* y0p = &y0.x;
      float* y1p = &y1.x;
      #pragma unroll
      for (int oo = 0; oo < 4; oo++) {
        y0p[oo] = (2.f * acc[jj][oo]     - g0[oo]     - sgn * gn[oo])     * invn;
        y1p[oo] = (2.f * acc[jj][oo + 4] - g0[oo + 4] - sgn * gn[oo + 4]) * invn;
      }
      *(float4*)(out + ((size_t)b * n + j) * CKD + (tx << 2)) = y0;
      *(float4*)(out + ((size_t)b * n + j) * CKD + 64 + (tx << 2)) = y1;
    }
  }
}

// coarsest map: y = x @ T0_w^T + T0_b
__global__ void t0_k(const float* __restrict__ xin, const float* __restrict__ w,
                     const float* __restrict__ bv, float* __restrict__ xout) {
  int idx = blockIdx.x * blockDim.x + threadIdx.x;
  if (idx >= BB * CC * KK) return;
  int k = idx & 3;
  int bc = idx >> 2;
  float a = bv[k];
  #pragma unroll
  for (int kp = 0; kp < 4; kp++) a = fmaf(xin[bc*4 + kp], w[k*4 + kp], a);
  xout[idx] = a;
}

__global__ void recon_k(const float* __restrict__ xin, const float* __restrict__ usl,
                        const float* __restrict__ udl,
                        const float* __restrict__ rce, const float* __restrict__ rco,
                        float* __restrict__ xout, int nh) {
  int idx = blockIdx.x * blockDim.x + threadIdx.x;
  if (idx >= BB * nh * CC) return;
  int c = idx & (CC - 1);
  int t = idx / CC;
  int j = t % nh;
  int b = t / nh;
  size_t ib = (((size_t)b * nh + j) * CC + c) * KK;
  float4 xv = *(const float4*)(xin + ib);
  float4 uv = *(const float4*)(usl + ib);
  float4 dv = *(const float4*)(udl + ib);
  float xx[8] = {xv.x+uv.x, xv.y+uv.y, xv.z+uv.z, xv.w+uv.w, dv.x, dv.y, dv.z, dv.w};
  float ev[4] = {0.f,0.f,0.f,0.f}, ov[4] = {0.f,0.f,0.f,0.f};
  #pragma unroll
  for (int p = 0; p < 8; p++) {
    float v = xx[p];
    #pragma unroll
    for (int k = 0; k < 4; k++) {
      ev[k] = fmaf(v, rce[p*4+k], ev[k]);
      ov[k] = fmaf(v, rco[p*4+k], ov[k]);
    }
  }
  size_t ob = (((size_t)b * (2*nh) + 2*j) * CC + c) * KK;
  *(float4*)(xout + ob) = make_float4(ev[0], ev[1], ev[2], ev[3]);
  *(float4*)(xout + ob + CC*KK) = make_float4(ov[0], ov[1], ov[2], ov[3]);
}

extern "C" void kernel_launch(void* const* d_in, const int* in_sizes, int n_in,
                              void* d_out, int out_size, void* d_ws, size_t ws_size,
                              hipStream_t stream) {
  const float* x   = (const float*)d_in[0];
  const float* wAr = (const float*)d_in[1];
  const float* wAi = (const float*)d_in[2];
  const float* wBr = (const float*)d_in[3];
  const float* wBi = (const float*)d_in[4];
  const float* wCr = (const float*)d_in[5];
  const float* wCi = (const float*)d_in[6];
  const float *ecs, *ecd, *rce, *rco, *t0w, *t0b;
  if (in_sizes[7] == 16) {
    t0w = (const float*)d_in[7];  t0b = (const float*)d_in[8];
    ecs = (const float*)d_in[9];  ecd = (const float*)d_in[10];
    rce = (const float*)d_in[11]; rco = (const float*)d_in[12];
  } else {
    ecs = (const float*)d_in[7];  ecd = (const float*)d_in[8];
    rce = (const float*)d_in[9];  rco = (const float*)d_in[10];
    t0w = (const float*)d_in[11]; t0b = (const float*)d_in[12];
  }

  int nh[NLEV], lv[NLEV];
  size_t twoff[NLEV], spoff[NLEV];   // spoff in float2 units within Dall/Sall/Uall/Vall
  size_t tacc = 0, spacc = 0;
  for (int q = 0; q < NLEV; q++) {
    nh[q] = NN >> (q + 1);
    int li = nh[q] / 2 + 1;
    lv[q] = li < AL ? li : AL;
    twoff[q] = tacc; tacc += (size_t)nh[q] * lv[q];
    spoff[q] = spacc; spacc += (size_t)BB * CKD * lv[q];
  }

  float* ws = (float*)d_ws;
  const size_t XS = (size_t)BB * (NN/2) * CKD;     // 8,388,608 floats
  float*  xb0  = ws;                               // XS floats
  float*  xb1  = xb0 + XS;                         // XS/2 floats (recon q=1 spills into Dall: dead then)
  float2* Dall = (float2*)(xb1 + XS / 2);          // spacc float2
  float2* Sall = Dall + spacc;
  float2* Uall = Sall + spacc;                     // also fwd partial scratch scrD (dead until mix)
  float2* Vall = Uall + spacc;
  float*  udT  = (float*)(Vall + spacc);           // XS floats (also stages d per level; Wt home)
  float*  usT  = udT + XS;                         // XS floats (also fwd partial scratch scrS)
  float2* tw   = (float2*)(usT + XS);
  float2* twT  = tw + tacc;
  // fwd partials: scrD spans Uall+Vall (2*spacc >= PMAX*262144),
  // scrS lives in usT (4.19M float2 capacity; usT only written by inv phase, later)
  float2* scrD = Uall;
  float2* scrS = (float2*)usT;
  // transposed weights live in udT..usT (dead between decompose and reconstruct):
  // 3 tensors x 128^3 float2 = 50.3 MB <= 67.1 MB
  float2* WtA = (float2*)udT;
  float2* WtB = WtA + (size_t)CKD * CKD * AL;
  float2* WtC = WtB + (size_t)CKD * CKD * AL;

  LevTab lt;
  for (int q = 0; q < NLEV; q++) { lt.off[q] = (int)twoff[q]; lt.n[q] = nh[q]; lt.l[q] = lv[q]; }
  lt.total = (int)tacc;
  twiddle_fill_k<<<dim3((unsigned)((tacc + 255) / 256)), 256, 0, stream>>>(tw, twT, lt);

  // ---------- decompose + forward DFT (all levels) ----------
  const float* cur = x;
  float* nxt = xb0;
  for (int q = 0; q < NLEV; q++) {
    int n2 = nh[q], l = lv[q];
    float* dtmp = udT;                 // transient d staging
    int tot = BB * n2 * CC;
    decompose_k<<<dim3((tot + 255) / 256), 256, 0, stream>>>(cur, nxt, dtmp, ecs, ecd, n2);

    int P = n2 / 128; if (P < 1) P = 1; if (P > PMAX) P = PMAX;
    int chunk = (((n2 + P - 1) / P) + 15) & ~15;
    float2* Dp = (P > 1) ? scrD : (Dall + spoff[q]);
    float2* Sp = (P > 1) ? scrS : (Sall + spoff[q]);
    fwd_dft_t<<<dim3((l + 63) / 64, BB * 2, 2 * P), 256, 0, stream>>>(dtmp, nxt, Dp, Sp,
                                                                      tw + twoff[q], n2, l,
                                                                      P, chunk);
    if (P > 1) {
      int cnt4 = (BB * CKD * l) / 2;   // float4 per partial
      reduce_k<<<dim3((2 * cnt4 + 255) / 256), 256, 0, stream>>>(
          (float4*)(Dall + spoff[q]), (float4*)(Sall + spoff[q]),
          (const float4*)scrD, (const float4*)scrS, cnt4, P);
    }
    cur = nxt;
    nxt = (nxt == xb0) ? xb1 : xb0;
  }

  // ---------- transpose weights into [m][i][o] float2 ----------
  wtr_k<<<dim3(CKD, 4, 3), 256, 0, stream>>>(wAr, wAi, wBr, wBi, wCr, wCi, WtA, WtB, WtC);

  // ---------- batched per-(lev,m) complex GEMM mode-mix ----------
  MixTab2 mt;
  int mc = 0;
  for (int q = 0; q < NLEV; q++) {
    mt.off[q] = (long long)spoff[q];
    mt.l[q] = lv[q];
    mt.mcum[q] = mc;
    mc += lv[q];
  }
  mix2_k<<<dim3((unsigned)mc), 256, 0, stream>>>(Dall, Sall, WtA, WtB, WtC, Uall, Vall, mt);

  // ---------- coarsest linear map ----------
  // cur holds s12 (in xb0 after 13 alternations); write t0 out to the other buffer
  float* t0out = (cur == xb0) ? xb1 : xb0;
  t0_k<<<dim3((BB * CC * KK + 255) / 256), 256, 0, stream>>>(cur, t0w, t0b, t0out);

  // ---------- reconstruct (inverse DFT deferred per level) ----------
  const float* rcur = t0out;
  float* rnxt = (t0out == xb0) ? xb1 : xb0;
  for (int q = NLEV - 1; q >= 0; q--) {
    int n2 = nh[q], l = lv[q];
    int nyq = (((n2 & 1) == 0) && (l == n2 / 2 + 1)) ? 1 : 0;
    inv_dft_t<<<dim3((n2 + 63) / 64, BB, 2), 256, 0, stream>>>(
        Uall + spoff[q], Vall + spoff[q], udT, usT, twT + twoff[q], n2, l, nyq);
    float* outp = (q == 0) ? (float*)d_out : rnxt;
    int tot = BB * n2 * CC;
    recon_k<<<dim3((tot + 255) / 256), 256, 0, stream>>>(rcur, usT, udT,
                                                         rce, rco, outp, n2);
    rcur = outp;
    rnxt = (rnxt == xb0) ? xb1 : xb0;
  }
}

// Round 4
// 1062.918 us; speedup vs baseline: 1.1249x; 1.1249x over previous
//
#include <hip/hip_runtime.h>

#define BB 16
#define CC 32
#define KK 4
#define CKD 128     // C*K
#define NN 8192
#define NLEV 13
#define AL 128      // ALPHA (weight mode-axis storage stride)

typedef unsigned short u16;
typedef __attribute__((ext_vector_type(8))) short bf16x8;
typedef __attribute__((ext_vector_type(8))) unsigned short ushort8;
typedef __attribute__((ext_vector_type(4))) float f32x4;

struct LevTab { int off[NLEV]; int n[NLEV]; int l[NLEV]; int total; };
struct MixTab2 { long long off[NLEV]; int l[NLEV]; int mcum[NLEV]; };

__device__ __forceinline__ u16 f2bh(float x) {
  union { float f; unsigned u; } v; v.f = x;
  unsigned r = (v.u + 0x7fffu + ((v.u >> 16) & 1u)) >> 16;
  return (u16)r;
}
__device__ __forceinline__ float bh2f(u16 h) {
  union { unsigned u; float f; } v; v.u = ((unsigned)h) << 16; return v.f;
}

// twT [m][j] float2 (inverse DFT) + 4 bf16 split planes [m][j] (forward MFMA)
__global__ void twiddle_fill_k(float2* __restrict__ twT,
                               u16* __restrict__ tch, u16* __restrict__ tcl,
                               u16* __restrict__ tsh, u16* __restrict__ tsl, LevTab t) {
  int idx = blockIdx.x * blockDim.x + threadIdx.x;
  if (idx >= t.total) return;
  int lev = 0;
  for (int q = 1; q < NLEV; q++) lev = (idx >= t.off[q]) ? q : lev;
  int r = idx - t.off[lev];
  int n = t.n[lev], l = t.l[lev];
  int j = r / l, m = r - j * l;
  long long pp = ((long long)j * (long long)m) % n;
  float ang = (float)((double)pp * (6.283185307179586476925286766559 / (double)n));
  float s, c;
  sincosf(ang, &s, &c);
  size_t o = (size_t)t.off[lev] + (size_t)m * n + j;
  twT[o] = make_float2(c, s);
  u16 h = f2bh(c); tch[o] = h; tcl[o] = f2bh(c - bh2f(h));
  h = f2bh(s);     tsh[o] = h; tsl[o] = f2bh(s - bh2f(h));
}

// fused decompose + transpose/convert:
// x:(B,2nh,CKD) fp32 -> s:(B,nh,CKD) fp32 (next level input)
//                    -> dh/dl/sh/sl: (B,CKD,nh) bf16 split planes (MFMA operands)
__global__ void decomp_t_k(const float* __restrict__ xin, float* __restrict__ sout,
                           u16* __restrict__ dh, u16* __restrict__ dl,
                           u16* __restrict__ sh, u16* __restrict__ sl,
                           const float* __restrict__ ecs, const float* __restrict__ ecd,
                           int nh) {
  int b = blockIdx.y;
  int j0 = blockIdx.x << 6;
  int t = threadIdx.x;
  int c = t & 31, j8 = t >> 5;
  int jbase = j0 + (j8 << 3);
  float s8[4][8], d8[4][8];
  #pragma unroll
  for (int jj = 0; jj < 8; jj++) {
    int j = jbase + jj;
    float sv[4] = {0.f,0.f,0.f,0.f}, dv[4] = {0.f,0.f,0.f,0.f};
    if (j < nh) {
      size_t ib = (((size_t)b * 2 * nh + 2 * j) * CC + c) * KK;
      float4 xe = *(const float4*)(xin + ib);
      float4 xo = *(const float4*)(xin + ib + CC * KK);
      float xa[8] = {xe.x, xe.y, xe.z, xe.w, xo.x, xo.y, xo.z, xo.w};
      #pragma unroll
      for (int p = 0; p < 8; p++) {
        float v = xa[p];
        #pragma unroll
        for (int k = 0; k < 4; k++) {
          sv[k] = fmaf(v, ecs[p*4+k], sv[k]);
          dv[k] = fmaf(v, ecd[p*4+k], dv[k]);
        }
      }
      size_t ob = (((size_t)b * nh + j) * CC + c) * KK;
      *(float4*)(sout + ob) = make_float4(sv[0], sv[1], sv[2], sv[3]);
    }
    #pragma unroll
    for (int k = 0; k < 4; k++) { s8[k][jj] = sv[k]; d8[k][jj] = dv[k]; }
  }
  if (jbase < nh) {
    bool full = (jbase + 8 <= nh);
    #pragma unroll
    for (int k = 0; k < 4; k++) {
      int i = (c << 2) + k;
      size_t rb = ((size_t)b * CKD + i) * nh + jbase;
      ushort8 vh, vl, wh, wl;
      #pragma unroll
      for (int jj = 0; jj < 8; jj++) {
        float dvv = d8[k][jj];
        u16 h = f2bh(dvv); vh[jj] = h; vl[jj] = f2bh(dvv - bh2f(h));
        float svv = s8[k][jj];
        h = f2bh(svv); wh[jj] = h; wl[jj] = f2bh(svv - bh2f(h));
      }
      if (full) {
        *(ushort8*)(dh + rb) = vh; *(ushort8*)(dl + rb) = vl;
        *(ushort8*)(sh + rb) = wh; *(ushort8*)(sl + rb) = wl;
      } else {
        int lim = nh - jbase;
        for (int jj = 0; jj < lim; jj++) {
          dh[rb+jj] = vh[jj]; dl[rb+jj] = vl[jj];
          sh[rb+jj] = wh[jj]; sl[rb+jj] = wl[jj];
        }
      }
    }
  }
}

// ---- MFMA forward DFT (split-bf16, 3 mfma per product) ----
// out[b][m][i] (float2): re = sum_j cos(jm)*v[j,i], im = -sum_j sin(jm)*v[j,i]
// block: 256 thr = 4 waves; tile 64m x 128i; wave = 32m x 64i (2 m-frag x 4 i-frag)
// grid: x = ceil(l/64), y = b, z = src*P + ks (K-split)
__global__ void __launch_bounds__(256)
fwd_mfma_k(const u16* __restrict__ dhp, const u16* __restrict__ dlp,
           const u16* __restrict__ shp, const u16* __restrict__ slp,
           const u16* __restrict__ tch, const u16* __restrict__ tcl,
           const u16* __restrict__ tsh, const u16* __restrict__ tsl,
           float2* __restrict__ Dp, float2* __restrict__ Sp,
           int n, int l, int P, int chunk) {
  __shared__ u16 Ts[4][64][40];    // cos_hi, cos_lo, sin_hi, sin_lo  [m][j]
  __shared__ u16 Vs[2][128][40];   // v_hi, v_lo                      [i][j]
  int zz = blockIdx.z;
  int srcs = (zz >= P) ? 1 : 0;
  int ks = zz - srcs * P;
  int b = blockIdx.y;
  int m0 = blockIdx.x << 6;
  const u16* vhp = srcs ? shp : dhp;
  const u16* vlp = srcs ? slp : dlp;
  float2* __restrict__ dst = (srcs ? Sp : Dp) + (size_t)ks * ((size_t)BB * CKD * l);
  int kstart = ks * chunk;
  int kcnt = n - kstart; if (kcnt > chunk) kcnt = chunk; if (kcnt < 0) kcnt = 0;
  int kmax = kstart + kcnt;
  int t = threadIdx.x, ln = t & 63, w = t >> 6;
  int wm = (w >> 1) << 5, wi = (w & 1) << 6;
  f32x4 accr[2][4], acci[2][4];
  #pragma unroll
  for (int a = 0; a < 2; a++)
    #pragma unroll
    for (int d = 0; d < 4; d++) {
      accr[a][d] = (f32x4){0.f,0.f,0.f,0.f};
      acci[a][d] = (f32x4){0.f,0.f,0.f,0.f};
    }
  const u16* tp0 = tch; const u16* tp1 = tcl; const u16* tp2 = tsh; const u16* tp3 = tsl;

  for (int js = 0; js < kcnt; js += 32) {
    #pragma unroll
    for (int it = 0; it < 4; it++) {     // stage T: 4 planes x 64 rows x 4 chunks
      int idx = t + (it << 8);
      int p = idx >> 8, r = (idx >> 2) & 63, jc = idx & 3;
      int jg = kstart + js + (jc << 3);
      ushort8 v = {0,0,0,0,0,0,0,0};
      int mrow = m0 + r;
      if (mrow < l && jg < kmax) {
        const u16* sp = (p == 0 ? tp0 : p == 1 ? tp1 : p == 2 ? tp2 : tp3)
                        + (size_t)mrow * n + jg;
        if (jg + 8 <= kmax) v = *(const ushort8*)sp;
        else { for (int e = 0; e < 8; e++) if (jg + e < kmax) v[e] = sp[e]; }
      }
      *(ushort8*)&Ts[p][r][jc << 3] = v;
    }
    #pragma unroll
    for (int it = 0; it < 4; it++) {     // stage V: 2 planes x 128 rows x 4 chunks
      int idx = t + (it << 8);
      int p = idx >> 9, r = (idx >> 2) & 127, jc = idx & 3;
      int jg = kstart + js + (jc << 3);
      ushort8 v = {0,0,0,0,0,0,0,0};
      if (jg < kmax) {
        const u16* bp = (p ? vlp : vhp) + ((size_t)b * CKD + r) * n + jg;
        if (jg + 8 <= kmax) v = *(const ushort8*)bp;
        else { for (int e = 0; e < 8; e++) if (jg + e < kmax) v[e] = bp[e]; }
      }
      *(ushort8*)&Vs[p][r][jc << 3] = v;
    }
    __syncthreads();
    int ac = (ln >> 4) << 3;
    #pragma unroll
    for (int fm = 0; fm < 2; fm++) {
      int ar = wm + (fm << 4) + (ln & 15);
      bf16x8 ach = *(const bf16x8*)&Ts[0][ar][ac];
      bf16x8 acl = *(const bf16x8*)&Ts[1][ar][ac];
      bf16x8 ash = *(const bf16x8*)&Ts[2][ar][ac];
      bf16x8 asl = *(const bf16x8*)&Ts[3][ar][ac];
      #pragma unroll
      for (int fi = 0; fi < 4; fi++) {
        int br = wi + (fi << 4) + (ln & 15);
        bf16x8 bh = *(const bf16x8*)&Vs[0][br][ac];
        bf16x8 bl = *(const bf16x8*)&Vs[1][br][ac];
        accr[fm][fi] = __builtin_amdgcn_mfma_f32_16x16x32_bf16(ach, bh, accr[fm][fi], 0, 0, 0);
        accr[fm][fi] = __builtin_amdgcn_mfma_f32_16x16x32_bf16(ach, bl, accr[fm][fi], 0, 0, 0);
        accr[fm][fi] = __builtin_amdgcn_mfma_f32_16x16x32_bf16(acl, bh, accr[fm][fi], 0, 0, 0);
        acci[fm][fi] = __builtin_amdgcn_mfma_f32_16x16x32_bf16(ash, bh, acci[fm][fi], 0, 0, 0);
        acci[fm][fi] = __builtin_amdgcn_mfma_f32_16x16x32_bf16(ash, bl, acci[fm][fi], 0, 0, 0);
        acci[fm][fi] = __builtin_amdgcn_mfma_f32_16x16x32_bf16(asl, bh, acci[fm][fi], 0, 0, 0);
      }
    }
    __syncthreads();
  }
  #pragma unroll
  for (int fm = 0; fm < 2; fm++)
    #pragma unroll
    for (int fi = 0; fi < 4; fi++) {
      int i = wi + (fi << 4) + (ln & 15);
      int mb = m0 + wm + (fm << 4) + ((ln >> 4) << 2);
      #pragma unroll
      for (int rg = 0; rg < 4; rg++) {
        int m = mb + rg;
        if (m < l)
          dst[((size_t)b * l + m) * CKD + i] = make_float2(accr[fm][fi][rg], -acci[fm][fi][rg]);
      }
    }
}

// sum P partial spectra (scratch) into compact Dall/Sall slots
__global__ void reduce_k(float4* __restrict__ dD, float4* __restrict__ dS,
                         const float4* __restrict__ pD, const float4* __restrict__ pS,
                         int cnt4, int P) {
  int idx = blockIdx.x * blockDim.x + threadIdx.x;
  if (idx >= 2 * cnt4) return;
  const float4* src = (idx < cnt4) ? pD : pS;
  float4* dst = (idx < cnt4) ? dD : dS;
  int e = (idx < cnt4) ? idx : idx - cnt4;
  float4 a = src[e];
  for (int p = 1; p < P; p++) {
    float4 v = src[(size_t)p * cnt4 + e];
    a.x += v.x; a.y += v.y; a.z += v.z; a.w += v.w;
  }
  dst[e] = a;
}

// weight transpose: W[i][o][m] (re,im separate) -> Wt[m][i][o] interleaved float2
__global__ void wtr_k(const float* __restrict__ Ar, const float* __restrict__ Ai,
                      const float* __restrict__ Br, const float* __restrict__ Bi,
                      const float* __restrict__ Cr, const float* __restrict__ Ci,
                      float2* __restrict__ WtA, float2* __restrict__ WtB,
                      float2* __restrict__ WtC) {
  __shared__ float2 Ts[32][130];
  int i = blockIdx.x;
  int o0 = blockIdx.y << 5;
  int z = blockIdx.z;
  const float* Wr = (z == 0) ? Ar : ((z == 1) ? Br : Cr);
  const float* Wi = (z == 0) ? Ai : ((z == 1) ? Bi : Ci);
  float2* Wt = (z == 0) ? WtA : ((z == 1) ? WtB : WtC);
  int tid = threadIdx.x;
  {
    int o = tid >> 3, m0 = (tid & 7) << 4;
    const float* rp = Wr + ((size_t)i * CKD + o0 + o) * AL + m0;
    const float* ip = Wi + ((size_t)i * CKD + o0 + o) * AL + m0;
    #pragma unroll
    for (int r = 0; r < 4; r++) {
      float4 vr = *(const float4*)(rp + r * 4);
      float4 vi = *(const float4*)(ip + r * 4);
      Ts[o][m0 + r*4 + 0] = make_float2(vr.x, vi.x);
      Ts[o][m0 + r*4 + 1] = make_float2(vr.y, vi.y);
      Ts[o][m0 + r*4 + 2] = make_float2(vr.z, vi.z);
      Ts[o][m0 + r*4 + 3] = make_float2(vr.w, vi.w);
    }
  }
  __syncthreads();
  {
    int m = tid >> 1, oh = (tid & 1) << 4;
    float2* wp = Wt + ((size_t)m * CKD + i) * CKD + o0 + oh;
    #pragma unroll
    for (int r = 0; r < 16; r += 2) {
      float2 e0 = Ts[oh + r][m];
      float2 e1 = Ts[oh + r + 1][m];
      *(float4*)(wp + r) = make_float4(e0.x, e0.y, e1.x, e1.y);
    }
  }
}

// batched per-(lev,m) complex GEMM; D/S now in [b][m][i] layout (contiguous stage)
__global__ void __launch_bounds__(256)
mix2_k(const float2* __restrict__ Dall, const float2* __restrict__ Sall,
       const float2* __restrict__ WA, const float2* __restrict__ WB,
       const float2* __restrict__ WC,
       float2* __restrict__ Uall, float2* __restrict__ Vall, MixTab2 mt) {
  __shared__ __align__(16) float2 Dl[CKD][BB];
  __shared__ __align__(16) float2 Sl[CKD][BB];
  int bx = blockIdx.x;
  int lev = 0;
  #pragma unroll
  for (int q = 1; q < NLEV; q++) lev = (bx >= mt.mcum[q]) ? q : lev;
  int m = bx - mt.mcum[lev];
  int l = mt.l[lev];
  const float2* __restrict__ D = Dall + mt.off[lev];
  const float2* __restrict__ S = Sall + mt.off[lev];
  float2* __restrict__ U = Uall + mt.off[lev];
  float2* __restrict__ V = Vall + mt.off[lev];
  int tid = threadIdx.x;
  int o = tid & (CKD - 1), bh = tid >> 7;
  {
    int bq = tid & 15, i0 = (tid >> 4) << 3;
    const float2* Db = D + ((size_t)bq * l + m) * CKD + i0;
    const float2* Sb = S + ((size_t)bq * l + m) * CKD + i0;
    #pragma unroll
    for (int r = 0; r < 8; r++) {
      Dl[i0 + r][bq] = Db[r];
      Sl[i0 + r][bq] = Sb[r];
    }
  }
  __syncthreads();
  float ur[8], ui[8], vr[8], vi[8];
  #pragma unroll
  for (int r = 0; r < 8; r++) { ur[r] = 0.f; ui[r] = 0.f; vr[r] = 0.f; vi[r] = 0.f; }
  const float2* wa = WA + (size_t)m * CKD * CKD + o;
  const float2* wb = WB + (size_t)m * CKD * CKD + o;
  const float2* wc = WC + (size_t)m * CKD * CKD + o;
  #pragma unroll 4
  for (int i = 0; i < CKD; i++) {
    float2 a  = wa[(size_t)i * CKD];
    float2 bw = wb[(size_t)i * CKD];
    float2 cw = wc[(size_t)i * CKD];
    float2 dv[8], sv[8];
    #pragma unroll
    for (int r = 0; r < 4; r++) {
      *(float4*)&dv[r*2] = *(const float4*)&Dl[i][(bh << 3) + r*2];
      *(float4*)&sv[r*2] = *(const float4*)&Sl[i][(bh << 3) + r*2];
    }
    #pragma unroll
    for (int r = 0; r < 8; r++) {
      float2 d = dv[r], s = sv[r];
      ur[r] = fmaf(d.x, a.x, ur[r]);  ur[r] = fmaf(-d.y, a.y, ur[r]);
      ur[r] = fmaf(s.x, bw.x, ur[r]); ur[r] = fmaf(-s.y, bw.y, ur[r]);
      ui[r] = fmaf(d.x, a.y, ui[r]);  ui[r] = fmaf(d.y, a.x, ui[r]);
      ui[r] = fmaf(s.x, bw.y, ui[r]); ui[r] = fmaf(s.y, bw.x, ui[r]);
      vr[r] = fmaf(d.x, cw.x, vr[r]); vr[r] = fmaf(-d.y, cw.y, vr[r]);
      vi[r] = fmaf(d.x, cw.y, vi[r]); vi[r] = fmaf(d.y, cw.x, vi[r]);
    }
  }
  #pragma unroll
  for (int r = 0; r < 8; r++) {
    int b = (bh << 3) + r;
    size_t ob = ((size_t)b * l + m) * CKD + o;
    U[ob] = make_float2(ur[r], ui[r]);
    V[ob] = make_float2(vr[r], vi[r]);
  }
}

// ---- tiled inverse DFT (64j x 128o tile, 4j x 8o per thread) ----
__global__ void __launch_bounds__(256)
inv_dft_t(const float2* __restrict__ Uf, const float2* __restrict__ Vf,
          float* __restrict__ ud, float* __restrict__ us,
          const float2* __restrict__ twT, int n, int l, int nyq) {
  __shared__ float Gr[16][128];
  __shared__ float Gi[16][128];
  __shared__ float2 Ts[16][64];
  int z = blockIdx.z;
  const float2* __restrict__ G = (z ? Vf : Uf);
  float* __restrict__ out = (z ? us : ud);
  int j0 = blockIdx.x << 6;
  int b = blockIdx.y;
  int tid = threadIdx.x;
  int tx = tid & 15, ty = tid >> 4;
  float acc[4][8];
  #pragma unroll
  for (int a = 0; a < 4; a++)
    #pragma unroll
    for (int d = 0; d < 8; d++) acc[a][d] = 0.f;

  for (int m0 = 0; m0 < l; m0 += 16) {
    #pragma unroll
    for (int it2 = 0; it2 < 4; it2++) {
      int idx = tid + (it2 << 8);
      int row = idx >> 6;
      int co = (idx & 63) << 1;
      float4 v = make_float4(0.f,0.f,0.f,0.f);
      if (m0 + row < l)
        v = *(const float4*)(G + ((size_t)b * l + m0 + row) * CKD + co);
      Gr[row][co] = v.x;   Gi[row][co] = v.y;
      Gr[row][co+1] = v.z; Gi[row][co+1] = v.w;
    }
    #pragma unroll
    for (int it2 = 0; it2 < 2; it2++) {
      int idx = tid + (it2 << 8);
      int row = idx >> 5;
      int cj = (idx & 31) << 1;
      float4 v = make_float4(0.f,0.f,0.f,0.f);
      if (m0 + row < l) {
        int jg = j0 + cj;
        if (jg + 1 < n) v = *(const float4*)(twT + (size_t)(m0 + row) * n + jg);
        else if (jg < n) { float2 t2 = twT[(size_t)(m0 + row) * n + jg]; v.x = t2.x; v.y = t2.y; }
      }
      *(float4*)&Ts[row][cj] = v;
    }
    __syncthreads();
    #pragma unroll
    for (int mm = 0; mm < 16; mm++) {
      float gr[8], gi[8];
      float2 cs[4];
      *(float4*)&gr[0] = *(const float4*)&Gr[mm][tx << 2];
      *(float4*)&gr[4] = *(const float4*)&Gr[mm][64 + (tx << 2)];
      *(float4*)&gi[0] = *(const float4*)&Gi[mm][tx << 2];
      *(float4*)&gi[4] = *(const float4*)&Gi[mm][64 + (tx << 2)];
      *(float4*)&cs[0] = *(const float4*)&Ts[mm][ty << 2];
      *(float4*)&cs[2] = *(const float4*)&Ts[mm][(ty << 2) + 2];
      #pragma unroll
      for (int jj = 0; jj < 4; jj++)
        #pragma unroll
        for (int oo = 0; oo < 8; oo++) {
          acc[jj][oo] = fmaf(gr[oo],  cs[jj].x, acc[jj][oo]);
          acc[jj][oo] = fmaf(gi[oo], -cs[jj].y, acc[jj][oo]);
        }
    }
    __syncthreads();
  }
  float invn = 1.f / (float)n;
  float g0[8], gn[8];
  #pragma unroll
  for (int oo = 0; oo < 8; oo++) {
    int o = ((oo >> 2) << 6) + (tx << 2) + (oo & 3);
    g0[oo] = G[((size_t)b * l) * CKD + o].x;
    gn[oo] = nyq ? G[((size_t)b * l + (l - 1)) * CKD + o].x : 0.f;
  }
  #pragma unroll
  for (int jj = 0; jj < 4; jj++) {
    int j = j0 + (ty << 2) + jj;
    if (j < n) {
      float sgn = (j & 1) ? -1.f : 1.f;
      float4 y0, y1;
      float* y0p = &y0.x;
      float* y1p = &y1.x;
      #pragma unroll
      for (int oo = 0; oo < 4; oo++) {
        y0p[oo] = (2.f * acc[jj][oo]     - g0[oo]     - sgn * gn[oo])     * invn;
        y1p[oo] = (2.f * acc[jj][oo + 4] - g0[oo + 4] - sgn * gn[oo + 4]) * invn;
      }
      *(float4*)(out + ((size_t)b * n + j) * CKD + (tx << 2)) = y0;
      *(float4*)(out + ((size_t)b * n + j) * CKD + 64 + (tx << 2)) = y1;
    }
  }
}

// coarsest map: y = x @ T0_w^T + T0_b
__global__ void t0_k(const float* __restrict__ xin, const float* __restrict__ w,
                     const float* __restrict__ bv, float* __restrict__ xout) {
  int idx = blockIdx.x * blockDim.x + threadIdx.x;
  if (idx >= BB * CC * KK) return;
  int k = idx & 3;
  int bc = idx >> 2;
  float a = bv[k];
  #pragma unroll
  for (int kp = 0; kp < 4; kp++) a = fmaf(xin[bc*4 + kp], w[k*4 + kp], a);
  xout[idx] = a;
}

__global__ void recon_k(const float* __restrict__ xin, const float* __restrict__ usl,
                        const float* __restrict__ udl,
                        const float* __restrict__ rce, const float* __restrict__ rco,
                        float* __restrict__ xout, int nh) {
  int idx = blockIdx.x * blockDim.x + threadIdx.x;
  if (idx >= BB * nh * CC) return;
  int c = idx & (CC - 1);
  int t = idx / CC;
  int j = t % nh;
  int b = t / nh;
  size_t ib = (((size_t)b * nh + j) * CC + c) * KK;
  float4 xv = *(const float4*)(xin + ib);
  float4 uv = *(const float4*)(usl + ib);
  float4 dv = *(const float4*)(udl + ib);
  float xx[8] = {xv.x+uv.x, xv.y+uv.y, xv.z+uv.z, xv.w+uv.w, dv.x, dv.y, dv.z, dv.w};
  float ev[4] = {0.f,0.f,0.f,0.f}, ov[4] = {0.f,0.f,0.f,0.f};
  #pragma unroll
  for (int p = 0; p < 8; p++) {
    float v = xx[p];
    #pragma unroll
    for (int k = 0; k < 4; k++) {
      ev[k] = fmaf(v, rce[p*4+k], ev[k]);
      ov[k] = fmaf(v, rco[p*4+k], ov[k]);
    }
  }
  size_t ob = (((size_t)b * (2*nh) + 2*j) * CC + c) * KK;
  *(float4*)(xout + ob) = make_float4(ev[0], ev[1], ev[2], ev[3]);
  *(float4*)(xout + ob + CC*KK) = make_float4(ov[0], ov[1], ov[2], ov[3]);
}

extern "C" void kernel_launch(void* const* d_in, const int* in_sizes, int n_in,
                              void* d_out, int out_size, void* d_ws, size_t ws_size,
                              hipStream_t stream) {
  const float* x   = (const float*)d_in[0];
  const float* wAr = (const float*)d_in[1];
  const float* wAi = (const float*)d_in[2];
  const float* wBr = (const float*)d_in[3];
  const float* wBi = (const float*)d_in[4];
  const float* wCr = (const float*)d_in[5];
  const float* wCi = (const float*)d_in[6];
  const float *ecs, *ecd, *rce, *rco, *t0w, *t0b;
  if (in_sizes[7] == 16) {
    t0w = (const float*)d_in[7];  t0b = (const float*)d_in[8];
    ecs = (const float*)d_in[9];  ecd = (const float*)d_in[10];
    rce = (const float*)d_in[11]; rco = (const float*)d_in[12];
  } else {
    ecs = (const float*)d_in[7];  ecd = (const float*)d_in[8];
    rce = (const float*)d_in[9];  rco = (const float*)d_in[10];
    t0w = (const float*)d_in[11]; t0b = (const float*)d_in[12];
  }

  int nh[NLEV], lv[NLEV];
  size_t twoff[NLEV], spoff[NLEV];
  size_t tacc = 0, spacc = 0;
  for (int q = 0; q < NLEV; q++) {
    nh[q] = NN >> (q + 1);
    int li = nh[q] / 2 + 1;
    lv[q] = li < AL ? li : AL;
    twoff[q] = tacc; tacc += (size_t)nh[q] * lv[q];
    spoff[q] = spacc; spacc += (size_t)BB * CKD * lv[q];
  }

  float* ws = (float*)d_ws;
  const size_t XS = (size_t)BB * (NN/2) * CKD;     // 8,388,608 floats
  float*  xb0  = ws;                               // XS floats
  float*  xb1  = xb0 + XS;                         // XS/2 floats
  float2* Dall = (float2*)(xb1 + XS / 2);          // spacc float2 each, [b][m][i]
  float2* Sall = Dall + spacc;
  float2* Uall = Sall + spacc;
  float2* Vall = Uall + spacc;
  float*  udT  = (float*)(Vall + spacc);           // XS floats: fwd = dh/dl planes; later Wt; recon = ud
  float*  usT  = udT + XS;                         // XS floats: fwd = sh/sl planes; recon = us
  float2* twT  = (float2*)(usT + XS);              // tacc float2
  u16* twCh = (u16*)(twT + tacc);                  // 4 x tacc u16 (same bytes as old tw)
  u16* twCl = twCh + tacc;
  u16* twSh = twCl + tacc;
  u16* twSl = twSh + tacc;
  // bf16 source planes: [b][CKD][n], level-0 sized (BB*CKD*NN/2 u16 = 16.78 MB each)
  u16* dhp = (u16*)udT;
  u16* dlp = dhp + (size_t)BB * CKD * (NN/2);
  u16* shp = (u16*)usT;
  u16* slp = shp + (size_t)BB * CKD * (NN/2);
  // fwd K-split partials: D -> Uall+Vall (dead until mix);
  // S -> xb1 at q=0, else the just-consumed cur buffer (dead after decomp)
  float2* scrD = Uall;
  // transposed weights (mix time; planes dead then): udT..usT span
  float2* WtA = (float2*)udT;
  float2* WtB = WtA + (size_t)CKD * CKD * AL;
  float2* WtC = WtB + (size_t)CKD * CKD * AL;

  LevTab lt;
  for (int q = 0; q < NLEV; q++) { lt.off[q] = (int)twoff[q]; lt.n[q] = nh[q]; lt.l[q] = lv[q]; }
  lt.total = (int)tacc;
  twiddle_fill_k<<<dim3((unsigned)((tacc + 255) / 256)), 256, 0, stream>>>(
      twT, twCh, twCl, twSh, twSl, lt);

  // ---------- decompose(+transpose/convert) + MFMA forward DFT ----------
  const float* cur = x;
  float* nxt = xb0;
  for (int q = 0; q < NLEV; q++) {
    int n2 = nh[q], l = lv[q];
    decomp_t_k<<<dim3((n2 + 63) / 64, BB), 256, 0, stream>>>(cur, nxt, dhp, dlp, shp, slp,
                                                             ecs, ecd, n2);
    int P = (n2 >= 512) ? 8 : ((n2 >= 64) ? n2 / 64 : 1);
    int chunk = ((n2 + P - 1) / P + 31) & ~31;
    int mtiles = (l + 63) / 64;
    float* curbuf = (q == 0) ? xb1 : ((q & 1) ? xb0 : xb1);
    float2* Dp = (P > 1) ? scrD : (Dall + spoff[q]);
    float2* Sp = (P > 1) ? (float2*)curbuf : (Sall + spoff[q]);
    fwd_mfma_k<<<dim3(mtiles, BB, 2 * P), 256, 0, stream>>>(
        dhp, dlp, shp, slp,
        twCh + twoff[q], twCl + twoff[q], twSh + twoff[q], twSl + twoff[q],
        Dp, Sp, n2, l, P, chunk);
    if (P > 1) {
      int cnt4 = (BB * CKD * l) / 2;
      reduce_k<<<dim3((2 * cnt4 + 255) / 256), 256, 0, stream>>>(
          (float4*)(Dall + spoff[q]), (float4*)(Sall + spoff[q]),
          (const float4*)scrD, (const float4*)Sp, cnt4, P);
    }
    cur = nxt;
    nxt = (nxt == xb0) ? xb1 : xb0;
  }

  // ---------- transpose weights into [m][i][o] float2 ----------
  wtr_k<<<dim3(CKD, 4, 3), 256, 0, stream>>>(wAr, wAi, wBr, wBi, wCr, wCi, WtA, WtB, WtC);

  // ---------- batched per-(lev,m) complex GEMM mode-mix ----------
  MixTab2 mt;
  int mc = 0;
  for (int q = 0; q < NLEV; q++) {
    mt.off[q] = (long long)spoff[q];
    mt.l[q] = lv[q];
    mt.mcum[q] = mc;
    mc += lv[q];
  }
  mix2_k<<<dim3((unsigned)mc), 256, 0, stream>>>(Dall, Sall, WtA, WtB, WtC, Uall, Vall, mt);

  // ---------- coarsest linear map ----------
  float* t0out = (cur == xb0) ? xb1 : xb0;
  t0_k<<<dim3((BB * CC * KK + 255) / 256), 256, 0, stream>>>(cur, t0w, t0b, t0out);

  // ---------- reconstruct (inverse DFT deferred per level) ----------
  const float* rcur = t0out;
  float* rnxt = (t0out == xb0) ? xb1 : xb0;
  for (int q = NLEV - 1; q >= 0; q--) {
    int n2 = nh[q], l = lv[q];
    int nyq = (((n2 & 1) == 0) && (l == n2 / 2 + 1)) ? 1 : 0;
    inv_dft_t<<<dim3((n2 + 63) / 64, BB, 2), 256, 0, stream>>>(
        Uall + spoff[q], Vall + spoff[q], udT, usT, twT + twoff[q], n2, l, nyq);
    float* outp = (q == 0) ? (float*)d_out : rnxt;
    int tot = BB * n2 * CC;
    recon_k<<<dim3((tot + 255) / 256), 256, 0, stream>>>(rcur, usT, udT,
                                                         rce, rco, outp, n2);
    rcur = outp;
    rnxt = (rnxt == xb0) ? xb1 : xb0;
  }
}